// Round 17
// baseline (117.594 us; speedup 1.0000x reference)
//
#include <hip/hip_runtime.h>
#include <stdint.h>

// Problem constants
#define BB 16
#define TT 4096
#define HH 64
#define MM 640    // HH*DD

#define TROWS 8           // t-rows per attn tile (halved: 2x blocks/CU vs champion)
#define PADF4 41          // LDS row stride in float4 (656 B)
#define ROWSF (PADF4 * 4) // 164 floats

// ---------------------------------------------------------------------------
// Kernel 1: ksum[b][m] = sum_t key[b][t][m]  (~27-30 us, near read roofline)
// ---------------------------------------------------------------------------
__global__ void __launch_bounds__(256)
ksum_kernel(const float* __restrict__ key, float* __restrict__ ksum) {
    int g = blockIdx.x * blockDim.x + threadIdx.x;   // b*160 + c
    int b = g / 160;
    int c = g % 160;
    int t0 = blockIdx.y * 32;

    const float4* p = reinterpret_cast<const float4*>(key)
                    + (size_t)b * TT * 160 + (size_t)t0 * 160 + c;

    float4 a0 = make_float4(0.f,0.f,0.f,0.f);
    float4 a1 = make_float4(0.f,0.f,0.f,0.f);
    float4 a2 = make_float4(0.f,0.f,0.f,0.f);
    float4 a3 = make_float4(0.f,0.f,0.f,0.f);
    #pragma unroll
    for (int i = 0; i < 32; i += 4) {
        float4 x0 = p[(size_t)(i + 0) * 160];
        float4 x1 = p[(size_t)(i + 1) * 160];
        float4 x2 = p[(size_t)(i + 2) * 160];
        float4 x3 = p[(size_t)(i + 3) * 160];
        a0.x += x0.x; a0.y += x0.y; a0.z += x0.z; a0.w += x0.w;
        a1.x += x1.x; a1.y += x1.y; a1.z += x1.z; a1.w += x1.w;
        a2.x += x2.x; a2.y += x2.y; a2.z += x2.z; a2.w += x2.w;
        a3.x += x3.x; a3.y += x3.y; a3.z += x3.z; a3.w += x3.w;
    }
    float sx = (a0.x + a1.x) + (a2.x + a3.x);
    float sy = (a0.y + a1.y) + (a2.y + a3.y);
    float sz = (a0.z + a1.z) + (a2.z + a3.z);
    float sw = (a0.w + a1.w) + (a2.w + a3.w);

    float* dst = ksum + b * MM + c * 4;
    atomicAdd(dst + 0, sx);
    atomicAdd(dst + 1, sy);
    atomicAdd(dst + 2, sz);
    atomicAdd(dst + 3, sw);
}

// ---------------------------------------------------------------------------
// Robust tanh via rcp (exp of negative arg only -> never overflows)
// ---------------------------------------------------------------------------
__device__ __forceinline__ float tanh_rcp(float x) {
    float ax = fabsf(x);
    float e2 = __expf(-2.0f * ax);
    float th = (1.0f - e2) * __builtin_amdgcn_rcpf(1.0f + e2);
    return copysignf(th, x);
}

// ---------------------------------------------------------------------------
// Kernel 2: champion structure, half-size tiles for 2x TLP.
//   TROWS=8, 128 threads, LDS 11.1 KB -> 14 blocks/CU = 28 waves/CU
//   (champion: 21 KB -> 7 blocks = 14 waves). Same coalescing: 5 f4/thread
//   over a combined q|v slot map (branch boundary 320 = wave-uniform).
//   1 output/thread (row = tid&7, head = tid>>3); 32B-segment stores.
// ---------------------------------------------------------------------------
__global__ void __launch_bounds__(128)
attn_kernel(const float* __restrict__ q,
            const float* __restrict__ v,
            const float* __restrict__ ksum,
            float* __restrict__ out) {
    __shared__ float qs[TROWS * ROWSF];   // 5248 B
    __shared__ float vs[TROWS * ROWSF];   // 5248 B
    __shared__ float ks_lds[160];         // 640 B

    const int tid = threadIdx.x;          // 0..127
    const int hg  = blockIdx.x;           // 0..3
    const int t0  = blockIdx.y * TROWS;
    const int b   = blockIdx.z;

    const float4* qg = reinterpret_cast<const float4*>(q)
                     + ((size_t)(b * TT + t0)) * 160 + hg * 40;
    const float4* vg = reinterpret_cast<const float4*>(v)
                     + ((size_t)(b * TT + t0)) * 160 + hg * 40;

    // ---- stage: 5 f4/thread over combined q|v slots (640 total) ----
    // slot: 0..319 = q tile (8 rows x 40 f4), 320..639 = v tile.
    // boundary 320 is a multiple of 64 -> qsel is wave-uniform per j.
    float4 rs[5];
    int   srow[5], scol[5], qsel[5];
    #pragma unroll
    for (int j = 0; j < 5; ++j) {
        int idx = tid + 128 * j;          // 0..639
        qsel[j] = (idx < 320);
        int s   = qsel[j] ? idx : idx - 320;
        srow[j] = s / 40;
        scol[j] = s % 40;
        const float4* base = qsel[j] ? qg : vg;
        rs[j] = base[(size_t)srow[j] * 160 + scol[j]];
    }
    if (tid < 40) {
        reinterpret_cast<float4*>(ks_lds)[tid] =
            reinterpret_cast<const float4*>(ksum + b * MM + hg * 160)[tid];
    }

    float4* qs4 = reinterpret_cast<float4*>(qs);
    float4* vs4 = reinterpret_cast<float4*>(vs);
    #pragma unroll
    for (int j = 0; j < 5; ++j) {
        float4* dst = qsel[j] ? qs4 : vs4;
        dst[srow[j] * PADF4 + scol[j]] = rs[j];
    }
    __syncthreads();

    // ---- compute: 1 (row, head) output per thread ----
    const float R = 0.316227766016838f;   // 1/sqrt(10)
    const int row  = tid & 7;
    const int head = tid >> 3;            // 0..15

    float ksr[10];
    #pragma unroll
    for (int d = 0; d < 10; ++d)
        ksr[d] = ks_lds[head * 10 + d] * R;

    const int lbase = row * ROWSF + head * 10;
    float sum = 0.f, dot = 0.f;
    #pragma unroll
    for (int d = 0; d < 10; ++d) {
        float e = __expf(tanh_rcp(qs[lbase + d] * ksr[d]));
        sum += e;
        dot += e * vs[lbase + d];
    }
    out[((size_t)(b * HH + hg * 16 + head)) * TT + t0 + row]
        = dot * __builtin_amdgcn_rcpf(sum);
}

// ---------------------------------------------------------------------------
extern "C" void kernel_launch(void* const* d_in, const int* in_sizes, int n_in,
                              void* d_out, int out_size, void* d_ws, size_t ws_size,
                              hipStream_t stream) {
    const float* q = (const float*)d_in[0];
    const float* k = (const float*)d_in[1];
    const float* v = (const float*)d_in[2];
    // d_in[3] = W, d_in[4] = b : dead code (softmax over size-1 axis == 1)
    float* out  = (float*)d_out;
    float* ksum = (float*)d_ws;    // B*M floats = 40 KB

    hipMemsetAsync(d_ws, 0, (size_t)BB * MM * sizeof(float), stream);
    ksum_kernel<<<dim3(10, 128), dim3(256), 0, stream>>>(k, ksum);
    // hg fastest, then t (512 tiles), then b
    attn_kernel<<<dim3(4, TT / TROWS, BB), dim3(128), 0, stream>>>(q, v, ksum, out);
}

// Round 18
// 110.962 us; speedup vs baseline: 1.0598x; 1.0598x over previous
//
#include <hip/hip_runtime.h>
#include <stdint.h>

// Problem constants
#define BB 16
#define TT 4096
#define HH 64
#define MM 640    // HH*DD

#define TROWS 32          // t-rows per attn tile (2x champion: amortize drains)
#define PADF4 41          // LDS row stride in float4 (656 B)
#define ROWSF (PADF4 * 4) // 164 floats

// ---------------------------------------------------------------------------
// Kernel 1: ksum[b][m] = sum_t key[b][t][m]  (~27-30 us, near read roofline)
// ---------------------------------------------------------------------------
__global__ void __launch_bounds__(256)
ksum_kernel(const float* __restrict__ key, float* __restrict__ ksum) {
    int g = blockIdx.x * blockDim.x + threadIdx.x;   // b*160 + c
    int b = g / 160;
    int c = g % 160;
    int t0 = blockIdx.y * 32;

    const float4* p = reinterpret_cast<const float4*>(key)
                    + (size_t)b * TT * 160 + (size_t)t0 * 160 + c;

    float4 a0 = make_float4(0.f,0.f,0.f,0.f);
    float4 a1 = make_float4(0.f,0.f,0.f,0.f);
    float4 a2 = make_float4(0.f,0.f,0.f,0.f);
    float4 a3 = make_float4(0.f,0.f,0.f,0.f);
    #pragma unroll
    for (int i = 0; i < 32; i += 4) {
        float4 x0 = p[(size_t)(i + 0) * 160];
        float4 x1 = p[(size_t)(i + 1) * 160];
        float4 x2 = p[(size_t)(i + 2) * 160];
        float4 x3 = p[(size_t)(i + 3) * 160];
        a0.x += x0.x; a0.y += x0.y; a0.z += x0.z; a0.w += x0.w;
        a1.x += x1.x; a1.y += x1.y; a1.z += x1.z; a1.w += x1.w;
        a2.x += x2.x; a2.y += x2.y; a2.z += x2.z; a2.w += x2.w;
        a3.x += x3.x; a3.y += x3.y; a3.z += x3.z; a3.w += x3.w;
    }
    float sx = (a0.x + a1.x) + (a2.x + a3.x);
    float sy = (a0.y + a1.y) + (a2.y + a3.y);
    float sz = (a0.z + a1.z) + (a2.z + a3.z);
    float sw = (a0.w + a1.w) + (a2.w + a3.w);

    float* dst = ksum + b * MM + c * 4;
    atomicAdd(dst + 0, sx);
    atomicAdd(dst + 1, sy);
    atomicAdd(dst + 2, sz);
    atomicAdd(dst + 3, sw);
}

// ---------------------------------------------------------------------------
// Robust tanh via rcp (exp of negative arg only -> never overflows)
// ---------------------------------------------------------------------------
__device__ __forceinline__ float tanh_rcp(float x) {
    float ax = fabsf(x);
    float e2 = __expf(-2.0f * ax);
    float th = (1.0f - e2) * __builtin_amdgcn_rcpf(1.0f + e2);
    return copysignf(th, x);
}

// ---------------------------------------------------------------------------
// Kernel 2: champion structure, TROWS=32 / 256 threads.
//   One vmcnt(0)+barrier drain now amortizes over 2x the streamed bytes
//   (the 8->16 row data showed drain amortization beats occupancy here).
//   LDS 42.6 KB -> 3 blocks/CU = 12 waves/CU.
//   - q/v: 10 coalesced f4/thread; q|v boundary at slot 1280 = 5*256
//     (wave-uniform split: j<5 -> q, j>=5 -> v)
//   - ksum: one f4 instruction (tid<40) -> LDS
//   - compute: 2 outputs/thread (p = tid + 256*o; row=p&31, head=p>>5);
//     stores: 128B segments per half-wave
// ---------------------------------------------------------------------------
__global__ void __launch_bounds__(256)
attn_kernel(const float* __restrict__ q,
            const float* __restrict__ v,
            const float* __restrict__ ksum,
            float* __restrict__ out) {
    __shared__ float qs[TROWS * ROWSF];   // 20992 B
    __shared__ float vs[TROWS * ROWSF];   // 20992 B
    __shared__ float ks_lds[160];         // 640 B

    const int tid = threadIdx.x;          // 0..255
    const int hg  = blockIdx.x;           // 0..3 (fastest)
    const int t0  = blockIdx.y * TROWS;
    const int b   = blockIdx.z;

    const float4* qg = reinterpret_cast<const float4*>(q)
                     + ((size_t)(b * TT + t0)) * 160 + hg * 40;
    const float4* vg = reinterpret_cast<const float4*>(v)
                     + ((size_t)(b * TT + t0)) * 160 + hg * 40;

    // ---- stage: 5 q-f4 + 5 v-f4 per thread (coalesced, 2KB/instr/wave) ----
    float4 rq[5], rv[5];
    #pragma unroll
    for (int j = 0; j < 5; ++j) {
        int s   = tid + 256 * j;          // 0..1279 (tile = 32 rows x 40 f4)
        int row = s / 40;
        int c   = s % 40;
        rq[j] = qg[(size_t)row * 160 + c];
        rv[j] = vg[(size_t)row * 160 + c];
    }
    if (tid < 40) {
        reinterpret_cast<float4*>(ks_lds)[tid] =
            reinterpret_cast<const float4*>(ksum + b * MM + hg * 160)[tid];
    }

    float4* qs4 = reinterpret_cast<float4*>(qs);
    float4* vs4 = reinterpret_cast<float4*>(vs);
    #pragma unroll
    for (int j = 0; j < 5; ++j) {
        int s   = tid + 256 * j;
        int row = s / 40;
        int c   = s % 40;
        qs4[row * PADF4 + c] = rq[j];
        vs4[row * PADF4 + c] = rv[j];
    }
    __syncthreads();

    // ---- ksum rows from LDS (broadcast within 32-lane groups) ----
    const float R = 0.316227766016838f;   // 1/sqrt(10)
    const int head0 = tid >> 5;           // 0..7 (second head = +8)
    const int row   = tid & 31;

    float ksr0[10], ksr1[10];
    #pragma unroll
    for (int d = 0; d < 10; ++d) {
        ksr0[d] = ks_lds[head0 * 10 + d] * R;
        ksr1[d] = ks_lds[(head0 + 8) * 10 + d] * R;
    }

    // ---- compute: 2 (row, head) outputs per thread ----
    #pragma unroll
    for (int o = 0; o < 2; ++o) {
        const int head  = head0 + o * 8;
        const int lbase = row * ROWSF + head * 10;
        const float* kk = o ? ksr1 : ksr0;
        float sum = 0.f, dot = 0.f;
        #pragma unroll
        for (int d = 0; d < 10; ++d) {
            float e = __expf(tanh_rcp(qs[lbase + d] * kk[d]));
            sum += e;
            dot += e * vs[lbase + d];
        }
        out[((size_t)(b * HH + hg * 16 + head)) * TT + t0 + row]
            = dot * __builtin_amdgcn_rcpf(sum);
    }
}

// ---------------------------------------------------------------------------
extern "C" void kernel_launch(void* const* d_in, const int* in_sizes, int n_in,
                              void* d_out, int out_size, void* d_ws, size_t ws_size,
                              hipStream_t stream) {
    const float* q = (const float*)d_in[0];
    const float* k = (const float*)d_in[1];
    const float* v = (const float*)d_in[2];
    // d_in[3] = W, d_in[4] = b : dead code (softmax over size-1 axis == 1)
    float* out  = (float*)d_out;
    float* ksum = (float*)d_ws;    // B*M floats = 40 KB

    hipMemsetAsync(d_ws, 0, (size_t)BB * MM * sizeof(float), stream);
    ksum_kernel<<<dim3(10, 128), dim3(256), 0, stream>>>(k, ksum);
    // hg fastest, then t (128 tiles of 32 rows), then b
    attn_kernel<<<dim3(4, TT / TROWS, BB), dim3(256), 0, stream>>>(q, v, ksum, out);
}